// Round 9
// baseline (1026.528 us; speedup 1.0000x reference)
//
#include <hip/hip_runtime.h>
#include <math.h>
#include <stdint.h>

#define VOL 110592   // 48*48*48
#define CINP 64      // input channels
#define PCH 64       // proj channels

typedef short short8 __attribute__((ext_vector_type(8)));
typedef float floatx4 __attribute__((ext_vector_type(4)));
typedef _Float16 h8 __attribute__((ext_vector_type(8)));

__device__ __forceinline__ ushort f2bf(float f) {
    union { float f; uint32_t u; } v; v.f = f;
    uint32_t r = v.u + 0x7FFFu + ((v.u >> 16) & 1u);   // RNE
    return (ushort)(r >> 16);
}

// ---------------------------------------------------------------------------
// 1x1x1 conv (64x64 matvec) + bias + channel L2-normalize. fp16 voxel-major
// output (post-norm values in [-1,1] -> fp16-safe).
__global__ __launch_bounds__(256) void proj_l2norm_kernel(
    const float* __restrict__ x,   // [64][VOL]
    const float* __restrict__ w,   // [64][64]
    const float* __restrict__ b,   // [64]
    _Float16* __restrict__ out)    // [VOL][64]
{
    const int v = blockIdx.x * 256 + threadIdx.x;
    float xr[CINP];
    for (int ci = 0; ci < CINP; ci++)
        xr[ci] = x[(size_t)ci * VOL + v];

    float acc[PCH];
    for (int c = 0; c < PCH; c++) {
        float a = b[c];
        #pragma unroll
        for (int ci = 0; ci < CINP; ci++)
            a = fmaf(w[c * CINP + ci], xr[ci], a);
        acc[c] = a;
    }
    float s = 0.f;
    #pragma unroll
    for (int c = 0; c < PCH; c++) s += acc[c] * acc[c];
    const float inv = 1.0f / fmaxf(sqrtf(s), 1e-12f);
    #pragma unroll
    for (int c = 0; c < PCH; c++)
        out[(size_t)v * PCH + c] = (_Float16)(acc[c] * inv);
}

// ---------------------------------------------------------------------------
// Correlation (343 offsets, edge-clamped) + softmax expected-offset, via
// f16 MFMA. One wave per 16-voxel x-tile (x-rows are 48 = 3 tiles, never
// crossing rows). For each of 49 (dz,dy) rows:
//   C'[x][u] = sum_c sp[x][c] * tp[u_clamped][c]   (16x16x64 = 2 chained
//   16x16x32 MFMAs per u-tile; 2 u-tiles u0 = x0-8, x0+8 cover dx in
//   [-3,3], each (x,dx) in exactly one tile).
// Edge padding = x-clamped B loads (clamp(u) duplicates tp[0]/tp[47], which
// is exactly the reference's edge-pad semantics). Fragment mapping identical
// to the conv kernel's (A: m=lane&15,k=q*8+e; B: n=lane&15; D: m=q*4+reg,
// n=lane&15). Softmax accumulators are per-lane (4 voxels x=q*4+r per lane)
// with loop-invariant validity/dx masks; final 16-lane butterfly reduce.
// corr values buffered in LDS [16][352] bf16 then dumped coalesced.
__global__ __launch_bounds__(64) void corr_mfma_kernel(
    const _Float16* __restrict__ sp,   // [VOL][64]
    const _Float16* __restrict__ tp,   // [VOL][64]
    ushort* __restrict__ featT)        // [VOL][352] bf16
{
    const int v0 = blockIdx.x * 16;
    const int x0 = v0 % 48;            // 0, 16, 32
    const int y  = (v0 / 48) % 48;
    const int z  = v0 / 2304;
    const int lane = threadIdx.x;      // 0..63
    const int l = lane & 15;
    const int q = lane >> 4;

    __shared__ __align__(16) ushort lds[16 * 352];   // 11.3 KB

    // A fragments (sp x-rows), loaded once, reused for all 49 rows.
    const _Float16* ap = sp + (size_t)(v0 + l) * 64 + q * 8;
    const h8 Afrag0 = *(const h8*)(ap);
    const h8 Afrag1 = *(const h8*)(ap + 32);

    // loop-invariant clamped B x-coordinates (u-tiles at x0-8, x0+8)
    const int xc0 = min(max(x0 - 8 + l, 0), 47);
    const int xc1 = min(max(x0 + 8 + l, 0), 47);

    // loop-invariant extraction constants; x = q*4 + r
    int  ldsoff[4];
    float fdx[4];
    int  vva[4], vsel[4];
    #pragma unroll
    for (int r = 0; r < 4; r++) {
        const int x = q * 4 + r;
        const int dx0 = l - 8 - x;     // u-tile 0
        const int dx1 = l + 8 - x;     // u-tile 1
        const int va = ((unsigned)(dx0 + 3) <= 6u);
        const int vb = ((unsigned)(dx1 + 3) <= 6u);
        const int dxs = va ? dx0 : dx1;
        vsel[r] = va;
        vva[r] = va | vb;
        fdx[r] = (float)dxs;
        ldsoff[r] = x * 352 + (dxs + 3);
    }

    float ssum[4] = {0.f, 0.f, 0.f, 0.f};
    float e0a[4]  = {0.f, 0.f, 0.f, 0.f};
    float e1a[4]  = {0.f, 0.f, 0.f, 0.f};
    float e2a[4]  = {0.f, 0.f, 0.f, 0.f};

    // B: 4 fragments per row = {utile0 k0, utile0 k1, utile1 k0, utile1 k1}
#define LOADB(BV, RR)                                                      \
    {                                                                      \
        const int rr_ = (RR);                                              \
        const int zc_ = min(max(z + rr_ / 7 - 3, 0), 47);                  \
        const int yc_ = min(max(y + rr_ % 7 - 3, 0), 47);                  \
        const size_t rb_ = (size_t)(zc_ * 2304 + yc_ * 48);                \
        const _Float16* p0_ = tp + (rb_ + xc0) * 64 + q * 8;               \
        const _Float16* p1_ = tp + (rb_ + xc1) * 64 + q * 8;               \
        BV[0] = *(const h8*)(p0_);                                         \
        BV[1] = *(const h8*)(p0_ + 32);                                    \
        BV[2] = *(const h8*)(p1_);                                         \
        BV[3] = *(const h8*)(p1_ + 32);                                    \
    }

#define ROW_BODY(RR, BU)                                                   \
    {                                                                      \
        const floatx4 z4_ = {0.f, 0.f, 0.f, 0.f};                          \
        floatx4 aA_ = __builtin_amdgcn_mfma_f32_16x16x32_f16(Afrag0, BU[0], z4_, 0, 0, 0); \
        aA_ = __builtin_amdgcn_mfma_f32_16x16x32_f16(Afrag1, BU[1], aA_, 0, 0, 0); \
        floatx4 aB_ = __builtin_amdgcn_mfma_f32_16x16x32_f16(Afrag0, BU[2], z4_, 0, 0, 0); \
        aB_ = __builtin_amdgcn_mfma_f32_16x16x32_f16(Afrag1, BU[3], aB_, 0, 0, 0); \
        const int rr_ = (RR);                                              \
        const float fdz_ = (float)(rr_ / 7 - 3);                           \
        const float fdy_ = (float)(rr_ % 7 - 3);                           \
        const int kb_ = rr_ * 7;                                           \
        _Pragma("unroll")                                                  \
        for (int r = 0; r < 4; r++) {                                      \
            const float val_ = vsel[r] ? aA_[r] : aB_[r];                  \
            const float e_ = vva[r] ? __expf(val_) : 0.f;                  \
            ssum[r] += e_;                                                 \
            e0a[r] = fmaf(e_, fdz_, e0a[r]);                               \
            e1a[r] = fmaf(e_, fdy_, e1a[r]);                               \
            e2a[r] = fmaf(e_, fdx[r], e2a[r]);                             \
            if (vva[r]) lds[ldsoff[r] + kb_] = f2bf(val_);                 \
        }                                                                  \
    }

    h8 B0[4], B1[4];
    LOADB(B0, 0)
    #pragma unroll 1
    for (int g = 0; g < 24; g++) {
        const int r0 = g * 2;
        LOADB(B1, r0 + 1)
        ROW_BODY(r0, B0)
        LOADB(B0, r0 + 2)          // g=23 loads row 48 (valid)
        ROW_BODY(r0 + 1, B1)
    }
    ROW_BODY(48, B0)
#undef ROW_BODY
#undef LOADB

    // butterfly reduce over the 16 l-lanes (masks touch only l bits)
    #pragma unroll
    for (int m = 1; m <= 8; m <<= 1) {
        #pragma unroll
        for (int r = 0; r < 4; r++) {
            ssum[r] += __shfl_xor(ssum[r], m);
            e0a[r]  += __shfl_xor(e0a[r], m);
            e1a[r]  += __shfl_xor(e1a[r], m);
            e2a[r]  += __shfl_xor(e2a[r], m);
        }
    }

    if (l == 0) {
        #pragma unroll
        for (int r = 0; r < 4; r++) {
            const float inv = 1.f / ssum[r];
            const int b = (q * 4 + r) * 352;
            lds[b + 343] = f2bf(e0a[r] * inv);
            lds[b + 344] = f2bf(e1a[r] * inv);
            lds[b + 345] = f2bf(e2a[r] * inv);
            #pragma unroll
            for (int j = 346; j < 352; j++) lds[b + j] = 0;
        }
    }
    __syncthreads();

    ushort* ob = featT + (size_t)v0 * 352;
    #pragma unroll
    for (int j = 0; j < 11; j++) {
        const int idx = lane + j * 64;          // 0..703
        const int row = idx / 44, col = (idx % 44) * 8;
        *(int4*)(ob + (size_t)row * 352 + col) = *(const int4*)(&lds[row * 352 + col]);
    }
}

// ---------------------------------------------------------------------------
// Weight pre-transpose: w[128][CIN][27] fp32 -> wT[27][128][CPAD] bf16 (pad 0).
// Block 0 also zero-fills the 16B global pad used by conv staging.
template<int CIN, int CPAD>
__global__ __launch_bounds__(256) void wprep_kernel(
    const float* __restrict__ w, ushort* __restrict__ wTo, float* __restrict__ zp)
{
    if (blockIdx.x == 0 && threadIdx.x < 4) zp[threadIdx.x] = 0.f;
    const int oc = blockIdx.x;
    for (int idx = threadIdx.x; idx < CPAD * 27; idx += 256) {
        const int icp = idx / 27, tap = idx - icp * 27;
        float val = 0.f;
        if (icp < CIN) val = w[((size_t)oc * CIN + icp) * 27 + tap];
        wTo[((size_t)tap * 128 + oc) * CPAD + icp] = f2bf(val);
    }
}

// ---------------------------------------------------------------------------
// Implicit-GEMM 3x3x3 conv via bf16 MFMA (zero padding). Round-8 version:
// LDS double-buffer + counted-vmcnt staging overlap + A/B register double
// buffers, one barrier per chunk, XCD-chunked swizzle, launch_bounds(256,2).
// Block: 128 voxels (2z x 4y x 16x) x 128 oc, 4 waves.
template<int CPAD>
__global__ __launch_bounds__(256, 2) void conv3_mfma_kernel(
    const ushort* __restrict__ xT,   // [VOL][CPAD] bf16
    const ushort* __restrict__ wT,   // [27][128][CPAD] bf16
    const float* __restrict__ bias,  // [128]
    const ushort* __restrict__ zpad, // 16B of zeros
    float* __restrict__ out)         // [128][VOL] fp32
{
    // XCD-chunked swizzle: grid 864, 8 XCDs -> 108 contiguous blocks per XCD.
    const int blk = (blockIdx.x % 8) * 108 + (blockIdx.x / 8);
    const int tx = blk % 3, ty = (blk / 3) % 12, tz = blk / 36;
    const int x0 = tx * 16, y0 = ty * 4, z0 = tz * 2;
    const int t = threadIdx.x;
    const int wave = t >> 6;
    const int lane = t & 63;
    const int l = lane & 15;
    const int q = lane >> 4;
    const int ocw = (wave & 1) * 64;
    const int mzw = wave >> 1;

    __shared__ __align__(16) ushort win[2][432 * 32];   // 54KB double buffer

    // per-lane staging byte offsets into xT (chunk 0), -1 = halo/OOB -> zpad.
    int off[7];
    #pragma unroll
    for (int it = 0; it < 7; it++) {
        const int c = wave + it * 4;
        off[it] = -1;
        if (c < 27) {
            const int i = c * 64 + lane;
            const int p = i >> 2, g = i & 3;
            const int wz = p / 108, pr = p - wz * 108;
            const int wy = pr / 18, wx = pr - wy * 18;
            const int gz = z0 + wz - 1, gy = y0 + wy - 1, gx = x0 + wx - 1;
            if ((unsigned)gx < 48u && (unsigned)gy < 48u && (unsigned)gz < 48u)
                off[it] = ((gz * 2304 + gy * 48 + gx) * CPAD + g * 8) * 2;
        }
    }

    floatx4 acc[4][4];   // acc[oc-subtile j][voxel-subtile mt]
    #pragma unroll
    for (int i = 0; i < 4; i++)
        #pragma unroll
        for (int j = 0; j < 4; j++)
            acc[i][j] = (floatx4){0.f, 0.f, 0.f, 0.f};

    const ushort* wbase = wT + (size_t)(ocw + l) * CPAD + q * 8;
    const int ldsbase = (mzw * 108 + l) * 32 + q * 8;

#define STAGE(CK, BUFP)                                                    \
    {                                                                      \
        const char* xck_ = (const char*)xT + (size_t)(CK) * 64;            \
        _Pragma("unroll")                                                  \
        for (int it_ = 0; it_ < 7; it_++) {                                \
            const int c_ = wave + it_ * 4;                                 \
            if (c_ < 27) {                                                 \
                const ushort* gp_ = (off[it_] >= 0)                        \
                    ? (const ushort*)(xck_ + off[it_]) : zpad;             \
                __builtin_amdgcn_global_load_lds(                          \
                    (const __attribute__((address_space(1))) uint32_t*)gp_,\
                    (__attribute__((address_space(3))) uint32_t*)((BUFP) + c_ * 512 + lane * 8), \
                    16, 0, 0);                                             \
            }                                                              \
        }                                                                  \
    }

    const int NCH = CPAD / 32;

    STAGE(0, &win[0][0]);
    __syncthreads();

    #pragma unroll 1
    for (int ck = 0; ck < NCH; ck++) {
        const ushort* cbuf = &win[ck & 1][0];
        ushort* nbuf = &win[(ck + 1) & 1][0];
        const ushort* wck = wbase + ck * 32;

        short8 A0[4], A1[4];
        A0[0] = *(const short8*)(wck);
        A0[1] = *(const short8*)(wck + 16 * CPAD);
        A0[2] = *(const short8*)(wck + 32 * CPAD);
        A0[3] = *(const short8*)(wck + 48 * CPAD);

        short8 B0[4], B1[4];
        B0[0] = *(const short8*)(&cbuf[ldsbase +    0]);
        B0[1] = *(const short8*)(&cbuf[ldsbase +  576]);
        B0[2] = *(const short8*)(&cbuf[ldsbase + 1152]);
        B0[3] = *(const short8*)(&cbuf[ldsbase + 1728]);

        if (ck + 1 < NCH) STAGE(ck + 1, nbuf);

#define CONV_BODY(TP, AU, AL, BU, BL)                                      \
        {                                                                  \
            const int tpn_ = (TP) + 1;                                     \
            if (tpn_ < 27) {                                               \
                const ushort* wp_ = wck + (size_t)tpn_ * (128 * CPAD);     \
                AL[0] = *(const short8*)(wp_);                             \
                AL[1] = *(const short8*)(wp_ + 16 * CPAD);                 \
                AL[2] = *(const short8*)(wp_ + 32 * CPAD);                 \
                AL[3] = *(const short8*)(wp_ + 48 * CPAD);                 \
                const int dzn_ = tpn_ / 9;                                 \
                const int dyn_ = (tpn_ / 3) % 3;                           \
                const int dxn_ = tpn_ % 3;                                 \
                const int pbn_ = ldsbase + (dzn_ * 108 + dyn_ * 18 + dxn_) * 32; \
                BL[0] = *(const short8*)(&cbuf[pbn_ +    0]);              \
                BL[1] = *(const short8*)(&cbuf[pbn_ +  576]);              \
                BL[2] = *(const short8*)(&cbuf[pbn_ + 1152]);              \
                BL[3] = *(const short8*)(&cbuf[pbn_ + 1728]);              \
            }                                                              \
            acc[0][0] = __builtin_amdgcn_mfma_f32_16x16x32_bf16(AU[0], BU[0], acc[0][0], 0, 0, 0); \
            acc[1][0] = __builtin_amdgcn_mfma_f32_16x16x32_bf16(AU[1], BU[0], acc[1][0], 0, 0, 0); \
            acc[2][0] = __builtin_amdgcn_mfma_f32_16x16x32_bf16(AU[2], BU[0], acc[2][0], 0, 0, 0); \
            acc[3][0] = __builtin_amdgcn_mfma_f32_16x16x32_bf16(AU[3], BU[0], acc[3][0], 0, 0, 0); \
            acc[0][1] = __builtin_amdgcn_mfma_f32_16x16x32_bf16(AU[0], BU[1], acc[0][1], 0, 0, 0); \
            acc[1][1] = __builtin_amdgcn_mfma_f32_16x16x32_bf16(AU[1], BU[1], acc[1][1], 0, 0, 0); \
            acc[2][1] = __builtin_amdgcn_mfma_f32_16x16x32_bf16(AU[2], BU[1], acc[2][1], 0, 0, 0); \
            acc[3][1] = __builtin_amdgcn_mfma_f32_16x16x32_bf16(AU[3], BU[1], acc[3][1], 0, 0, 0); \
            acc[0][2] = __builtin_amdgcn_mfma_f32_16x16x32_bf16(AU[0], BU[2], acc[0][2], 0, 0, 0); \
            acc[1][2] = __builtin_amdgcn_mfma_f32_16x16x32_bf16(AU[1], BU[2], acc[1][2], 0, 0, 0); \
            acc[2][2] = __builtin_amdgcn_mfma_f32_16x16x32_bf16(AU[2], BU[2], acc[2][2], 0, 0, 0); \
            acc[3][2] = __builtin_amdgcn_mfma_f32_16x16x32_bf16(AU[3], BU[2], acc[3][2], 0, 0, 0); \
            acc[0][3] = __builtin_amdgcn_mfma_f32_16x16x32_bf16(AU[0], BU[3], acc[0][3], 0, 0, 0); \
            acc[1][3] = __builtin_amdgcn_mfma_f32_16x16x32_bf16(AU[1], BU[3], acc[1][3], 0, 0, 0); \
            acc[2][3] = __builtin_amdgcn_mfma_f32_16x16x32_bf16(AU[2], BU[3], acc[2][3], 0, 0, 0); \
            acc[3][3] = __builtin_amdgcn_mfma_f32_16x16x32_bf16(AU[3], BU[3], acc[3][3], 0, 0, 0); \
        }

        #pragma unroll 1
        for (int tg = 0; tg < 13; tg++) {
            const int tp = tg * 2;
            CONV_BODY(tp, A0, A1, B0, B1);
            CONV_BODY(tp + 1, A1, A0, B1, B0);
        }
        CONV_BODY(26, A0, A1, B0, B1);
#undef CONV_BODY

        __syncthreads();
    }
#undef STAGE

    #pragma unroll
    for (int nt = 0; nt < 4; nt++) {
        const int ocb = ocw + nt * 16 + q * 4;
        const float4 bv = *(const float4*)(bias + ocb);
        #pragma unroll
        for (int mt = 0; mt < 4; mt++) {
            const int v = (z0 + mzw) * 2304 + (y0 + mt) * 48 + x0 + l;
            out[(size_t)(ocb + 0) * VOL + v] = acc[nt][mt][0] + bv.x;
            out[(size_t)(ocb + 1) * VOL + v] = acc[nt][mt][1] + bv.y;
            out[(size_t)(ocb + 2) * VOL + v] = acc[nt][mt][2] + bv.z;
            out[(size_t)(ocb + 3) * VOL + v] = acc[nt][mt][3] + bv.w;
        }
    }
}

// ---------------------------------------------------------------------------
// Two-phase per-channel stats. Phase 1: grid (128, 8) partial sums.
__global__ __launch_bounds__(256) void chan_stats_part_kernel(
    const float* __restrict__ x, float* __restrict__ pstats /* [128][8][2] */)
{
    const int c = blockIdx.x, g = blockIdx.y;
    const float4* p = (const float4*)(x + (size_t)c * VOL) + g * 3456;
    float s = 0.f, s2 = 0.f;
    #pragma unroll
    for (int j = 0; j < 14; j++) {
        const int i = threadIdx.x + j * 256;
        if (i < 3456) {
            const float4 v = p[i];
            s += v.x + v.y + v.z + v.w;
            s2 = fmaf(v.x, v.x, fmaf(v.y, v.y, fmaf(v.z, v.z, fmaf(v.w, v.w, s2))));
        }
    }
    s  += __shfl_down(s, 32);  s  += __shfl_down(s, 16);
    s  += __shfl_down(s, 8);   s  += __shfl_down(s, 4);
    s  += __shfl_down(s, 2);   s  += __shfl_down(s, 1);
    s2 += __shfl_down(s2, 32); s2 += __shfl_down(s2, 16);
    s2 += __shfl_down(s2, 8);  s2 += __shfl_down(s2, 4);
    s2 += __shfl_down(s2, 2);  s2 += __shfl_down(s2, 1);
    __shared__ float rs[4], rs2[4];
    if ((threadIdx.x & 63) == 0) {
        rs[threadIdx.x >> 6] = s;
        rs2[threadIdx.x >> 6] = s2;
    }
    __syncthreads();
    if (threadIdx.x == 0) {
        pstats[(c * 8 + g) * 2]     = rs[0] + rs[1] + rs[2] + rs[3];
        pstats[(c * 8 + g) * 2 + 1] = rs2[0] + rs2[1] + rs2[2] + rs2[3];
    }
}

// Phase 2: 1 block, 128 threads -> mean/rstd.
__global__ __launch_bounds__(128) void chan_stats_fin_kernel(
    const float* __restrict__ pstats, float* __restrict__ stats /* [128][2] */)
{
    const int c = threadIdx.x;
    float s = 0.f, s2 = 0.f;
    #pragma unroll
    for (int g = 0; g < 8; g++) {
        s  += pstats[(c * 8 + g) * 2];
        s2 += pstats[(c * 8 + g) * 2 + 1];
    }
    const float mean = s / (float)VOL;
    const float var  = s2 / (float)VOL - mean * mean;
    stats[c * 2]     = mean;
    stats[c * 2 + 1] = rsqrtf(var + 1e-5f);
}

__device__ __forceinline__ float gelu_exact(float h)
{
    return 0.5f * h * (1.f + erff(h * 0.70710678118654752f));
}

// Elementwise instance-norm apply + exact GELU (final output, fp32).
__global__ __launch_bounds__(256) void norm_gelu_kernel(
    const float* __restrict__ x, const float* __restrict__ stats,
    float* __restrict__ out)
{
    const size_t i = (size_t)blockIdx.x * 256 + threadIdx.x;  // float4 index
    const int c = (int)(i / (VOL / 4));
    const float mean = stats[c * 2], rstd = stats[c * 2 + 1];
    const float4 xv = ((const float4*)x)[i];
    float4 o;
    o.x = gelu_exact((xv.x - mean) * rstd);
    o.y = gelu_exact((xv.y - mean) * rstd);
    o.z = gelu_exact((xv.z - mean) * rstd);
    o.w = gelu_exact((xv.w - mean) * rstd);
    ((float4*)out)[i] = o;
}

// ---------------------------------------------------------------------------
// Fused: instance-norm apply + GELU + transpose [128][VOL] fp32 -> [VOL][128]
// bf16 (32x32 LDS tiles).
__global__ __launch_bounds__(256) void norm_gelu_transpose_kernel(
    const float* __restrict__ x, const float* __restrict__ stats,
    ushort* __restrict__ outT)
{
    __shared__ float tile[32][33];
    const int v0 = blockIdx.x * 32;
    const int c0 = blockIdx.y * 32;
    const int t = threadIdx.x;
    const int vl = t & 31, cl = t >> 5;
    #pragma unroll
    for (int i = 0; i < 4; i++) {
        const int c = c0 + cl + i * 8;
        const float mean = stats[c * 2], rstd = stats[c * 2 + 1];
        const float val = x[(size_t)c * VOL + v0 + vl];
        tile[cl + i * 8][vl] = gelu_exact((val - mean) * rstd);
    }
    __syncthreads();
    const int vw = t >> 3, cg = t & 7;
    ushort4 o;
    o.x = f2bf(tile[cg * 4 + 0][vw]);
    o.y = f2bf(tile[cg * 4 + 1][vw]);
    o.z = f2bf(tile[cg * 4 + 2][vw]);
    o.w = f2bf(tile[cg * 4 + 3][vw]);
    *(ushort4*)(outT + (size_t)(v0 + vw) * 128 + c0 + cg * 4) = o;
}

// ---------------------------------------------------------------------------
extern "C" void kernel_launch(void* const* d_in, const int* in_sizes, int n_in,
                              void* d_out, int out_size, void* d_ws, size_t ws_size,
                              hipStream_t stream)
{
    const float* src = (const float*)d_in[0];
    const float* tgt = (const float*)d_in[1];
    const float* psw = (const float*)d_in[2];
    const float* psb = (const float*)d_in[3];
    const float* ptw = (const float*)d_in[4];
    const float* ptb = (const float*)d_in[5];
    const float* e1w = (const float*)d_in[6];
    const float* e1b = (const float*)d_in[7];
    const float* e2w = (const float*)d_in[8];
    const float* e2b = (const float*)d_in[9];

    float* ws = (float*)d_ws;
    // Workspace (float-unit offsets; V = VOL):
    //   sp/tp fp16 [0,64V)        dead after corr -> h1 (fp32) reuses [0,128V)
    //   featT bf16 [128V,304V)    dead after conv1 -> h2 reuses [128V,256V)
    //   h1T bf16 [304V,368V)
    //   w1T bf16 [368V..), w2T, stats, pstats, zpad
    _Float16* sp  = (_Float16*)ws;
    _Float16* tp  = (_Float16*)(ws + (size_t)32 * VOL);
    ushort* featT = (ushort*)(ws + (size_t)128 * VOL);
    float*  h1    = ws;
    float*  h2    = ws + (size_t)128 * VOL;
    ushort* h1T   = (ushort*)(ws + (size_t)304 * VOL);
    float*  w1Tf  = ws + (size_t)368 * VOL;
    ushort* w1T   = (ushort*)w1Tf;
    float*  w2Tf  = w1Tf + 608256;           // 27*128*352 ushorts
    ushort* w2T   = (ushort*)w2Tf;
    float*  stats = w2Tf + 221184;           // 27*128*128 ushorts
    float*  pstats = stats + 256;            // 128*8*2 floats
    float*  zpadf  = pstats + 2048;          // 16B zero pad for conv staging
    const ushort* zpad = (const ushort*)zpadf;

    wprep_kernel<346, 352><<<128, 256, 0, stream>>>(e1w, w1T, zpadf);
    wprep_kernel<128, 128><<<128, 256, 0, stream>>>(e2w, w2T, zpadf);

    proj_l2norm_kernel<<<432, 256, 0, stream>>>(src, psw, psb, sp);
    proj_l2norm_kernel<<<432, 256, 0, stream>>>(tgt, ptw, ptb, tp);
    corr_mfma_kernel<<<VOL / 16, 64, 0, stream>>>(sp, tp, featT);

    conv3_mfma_kernel<352><<<864, 256, 0, stream>>>(featT, w1T, e1b, zpad, h1);
    chan_stats_part_kernel<<<dim3(128, 8), 256, 0, stream>>>(h1, pstats);
    chan_stats_fin_kernel<<<1, 128, 0, stream>>>(pstats, stats);
    norm_gelu_transpose_kernel<<<dim3(3456, 4), 256, 0, stream>>>(h1, stats, h1T);

    conv3_mfma_kernel<128><<<864, 256, 0, stream>>>(h1T, w2T, e2b, zpad, h2);
    chan_stats_part_kernel<<<dim3(128, 8), 256, 0, stream>>>(h2, pstats);
    chan_stats_fin_kernel<<<1, 128, 0, stream>>>(pstats, stats);
    norm_gelu_kernel<<<(128 * VOL) / 1024, 256, 0, stream>>>(h2, stats, (float*)d_out);
}

// Round 10
// 980.842 us; speedup vs baseline: 1.0466x; 1.0466x over previous
//
#include <hip/hip_runtime.h>
#include <math.h>
#include <stdint.h>

#define VOL 110592   // 48*48*48
#define CINP 64      // input channels
#define PCH 64       // proj channels

typedef short short8 __attribute__((ext_vector_type(8)));
typedef float floatx4 __attribute__((ext_vector_type(4)));
typedef _Float16 h8 __attribute__((ext_vector_type(8)));

__device__ __forceinline__ ushort f2bf(float f) {
    union { float f; uint32_t u; } v; v.f = f;
    uint32_t r = v.u + 0x7FFFu + ((v.u >> 16) & 1u);   // RNE
    return (ushort)(r >> 16);
}

// ---------------------------------------------------------------------------
// 1x1x1 conv (64x64 matvec) + bias + channel L2-normalize. fp16 voxel-major
// output (post-norm values in [-1,1] -> fp16-safe).
// This round: FULL unroll pragmas on the xr-load loop and the outer matvec
// loop. Without them the compiler can leave the 64-trip loops rolled ->
// xr[]/acc[] are runtime-indexed -> allocated in SCRATCH (rule #20), and the
// unrolled inner loop then does 4096 scratch loads/thread (~1.8 GB/call).
// With static indexing both arrays live in registers (~150 VGPR, no spill).
// FMA order unchanged -> numerics identical.
__global__ __launch_bounds__(256) void proj_l2norm_kernel(
    const float* __restrict__ x,   // [64][VOL]
    const float* __restrict__ w,   // [64][64]
    const float* __restrict__ b,   // [64]
    _Float16* __restrict__ out)    // [VOL][64]
{
    const int v = blockIdx.x * 256 + threadIdx.x;
    float xr[CINP];
    #pragma unroll
    for (int ci = 0; ci < CINP; ci++)
        xr[ci] = x[(size_t)ci * VOL + v];

    float acc[PCH];
    #pragma unroll
    for (int c = 0; c < PCH; c++) {
        float a = b[c];
        #pragma unroll
        for (int ci = 0; ci < CINP; ci++)
            a = fmaf(w[c * CINP + ci], xr[ci], a);
        acc[c] = a;
    }
    float s = 0.f;
    #pragma unroll
    for (int c = 0; c < PCH; c++) s += acc[c] * acc[c];
    const float inv = 1.0f / fmaxf(sqrtf(s), 1e-12f);
    #pragma unroll
    for (int c = 0; c < PCH; c++)
        out[(size_t)v * PCH + c] = (_Float16)(acc[c] * inv);
}

// ---------------------------------------------------------------------------
// Correlation (343 offsets, edge-clamped) + softmax expected-offset, via
// f16 MFMA. One wave per 16-voxel x-tile. Round-9 version (verified).
__global__ __launch_bounds__(64) void corr_mfma_kernel(
    const _Float16* __restrict__ sp,   // [VOL][64]
    const _Float16* __restrict__ tp,   // [VOL][64]
    ushort* __restrict__ featT)        // [VOL][352] bf16
{
    const int v0 = blockIdx.x * 16;
    const int x0 = v0 % 48;            // 0, 16, 32
    const int y  = (v0 / 48) % 48;
    const int z  = v0 / 2304;
    const int lane = threadIdx.x;      // 0..63
    const int l = lane & 15;
    const int q = lane >> 4;

    __shared__ __align__(16) ushort lds[16 * 352];   // 11.3 KB

    // A fragments (sp x-rows), loaded once, reused for all 49 rows.
    const _Float16* ap = sp + (size_t)(v0 + l) * 64 + q * 8;
    const h8 Afrag0 = *(const h8*)(ap);
    const h8 Afrag1 = *(const h8*)(ap + 32);

    // loop-invariant clamped B x-coordinates (u-tiles at x0-8, x0+8)
    const int xc0 = min(max(x0 - 8 + l, 0), 47);
    const int xc1 = min(max(x0 + 8 + l, 0), 47);

    // loop-invariant extraction constants; x = q*4 + r
    int  ldsoff[4];
    float fdx[4];
    int  vva[4], vsel[4];
    #pragma unroll
    for (int r = 0; r < 4; r++) {
        const int x = q * 4 + r;
        const int dx0 = l - 8 - x;     // u-tile 0
        const int dx1 = l + 8 - x;     // u-tile 1
        const int va = ((unsigned)(dx0 + 3) <= 6u);
        const int vb = ((unsigned)(dx1 + 3) <= 6u);
        const int dxs = va ? dx0 : dx1;
        vsel[r] = va;
        vva[r] = va | vb;
        fdx[r] = (float)dxs;
        ldsoff[r] = x * 352 + (dxs + 3);
    }

    float ssum[4] = {0.f, 0.f, 0.f, 0.f};
    float e0a[4]  = {0.f, 0.f, 0.f, 0.f};
    float e1a[4]  = {0.f, 0.f, 0.f, 0.f};
    float e2a[4]  = {0.f, 0.f, 0.f, 0.f};

    // B: 4 fragments per row = {utile0 k0, utile0 k1, utile1 k0, utile1 k1}
#define LOADB(BV, RR)                                                      \
    {                                                                      \
        const int rr_ = (RR);                                              \
        const int zc_ = min(max(z + rr_ / 7 - 3, 0), 47);                  \
        const int yc_ = min(max(y + rr_ % 7 - 3, 0), 47);                  \
        const size_t rb_ = (size_t)(zc_ * 2304 + yc_ * 48);                \
        const _Float16* p0_ = tp + (rb_ + xc0) * 64 + q * 8;               \
        const _Float16* p1_ = tp + (rb_ + xc1) * 64 + q * 8;               \
        BV[0] = *(const h8*)(p0_);                                         \
        BV[1] = *(const h8*)(p0_ + 32);                                    \
        BV[2] = *(const h8*)(p1_);                                         \
        BV[3] = *(const h8*)(p1_ + 32);                                    \
    }

#define ROW_BODY(RR, BU)                                                   \
    {                                                                      \
        const floatx4 z4_ = {0.f, 0.f, 0.f, 0.f};                          \
        floatx4 aA_ = __builtin_amdgcn_mfma_f32_16x16x32_f16(Afrag0, BU[0], z4_, 0, 0, 0); \
        aA_ = __builtin_amdgcn_mfma_f32_16x16x32_f16(Afrag1, BU[1], aA_, 0, 0, 0); \
        floatx4 aB_ = __builtin_amdgcn_mfma_f32_16x16x32_f16(Afrag0, BU[2], z4_, 0, 0, 0); \
        aB_ = __builtin_amdgcn_mfma_f32_16x16x32_f16(Afrag1, BU[3], aB_, 0, 0, 0); \
        const int rr_ = (RR);                                              \
        const float fdz_ = (float)(rr_ / 7 - 3);                           \
        const float fdy_ = (float)(rr_ % 7 - 3);                           \
        const int kb_ = rr_ * 7;                                           \
        _Pragma("unroll")                                                  \
        for (int r = 0; r < 4; r++) {                                      \
            const float val_ = vsel[r] ? aA_[r] : aB_[r];                  \
            const float e_ = vva[r] ? __expf(val_) : 0.f;                  \
            ssum[r] += e_;                                                 \
            e0a[r] = fmaf(e_, fdz_, e0a[r]);                               \
            e1a[r] = fmaf(e_, fdy_, e1a[r]);                               \
            e2a[r] = fmaf(e_, fdx[r], e2a[r]);                             \
            if (vva[r]) lds[ldsoff[r] + kb_] = f2bf(val_);                 \
        }                                                                  \
    }

    h8 B0[4], B1[4];
    LOADB(B0, 0)
    #pragma unroll 1
    for (int g = 0; g < 24; g++) {
        const int r0 = g * 2;
        LOADB(B1, r0 + 1)
        ROW_BODY(r0, B0)
        LOADB(B0, r0 + 2)          // g=23 loads row 48 (valid)
        ROW_BODY(r0 + 1, B1)
    }
    ROW_BODY(48, B0)
#undef ROW_BODY
#undef LOADB

    // butterfly reduce over the 16 l-lanes (masks touch only l bits)
    #pragma unroll
    for (int m = 1; m <= 8; m <<= 1) {
        #pragma unroll
        for (int r = 0; r < 4; r++) {
            ssum[r] += __shfl_xor(ssum[r], m);
            e0a[r]  += __shfl_xor(e0a[r], m);
            e1a[r]  += __shfl_xor(e1a[r], m);
            e2a[r]  += __shfl_xor(e2a[r], m);
        }
    }

    if (l == 0) {
        #pragma unroll
        for (int r = 0; r < 4; r++) {
            const float inv = 1.f / ssum[r];
            const int b = (q * 4 + r) * 352;
            lds[b + 343] = f2bf(e0a[r] * inv);
            lds[b + 344] = f2bf(e1a[r] * inv);
            lds[b + 345] = f2bf(e2a[r] * inv);
            #pragma unroll
            for (int j = 346; j < 352; j++) lds[b + j] = 0;
        }
    }
    __syncthreads();

    ushort* ob = featT + (size_t)v0 * 352;
    #pragma unroll
    for (int j = 0; j < 11; j++) {
        const int idx = lane + j * 64;          // 0..703
        const int row = idx / 44, col = (idx % 44) * 8;
        *(int4*)(ob + (size_t)row * 352 + col) = *(const int4*)(&lds[row * 352 + col]);
    }
}

// ---------------------------------------------------------------------------
// Weight pre-transpose: w[128][CIN][27] fp32 -> wT[27][128][CPAD] bf16 (pad 0).
// Block 0 also zero-fills the 16B global pad used by conv staging.
template<int CIN, int CPAD>
__global__ __launch_bounds__(256) void wprep_kernel(
    const float* __restrict__ w, ushort* __restrict__ wTo, float* __restrict__ zp)
{
    if (blockIdx.x == 0 && threadIdx.x < 4) zp[threadIdx.x] = 0.f;
    const int oc = blockIdx.x;
    for (int idx = threadIdx.x; idx < CPAD * 27; idx += 256) {
        const int icp = idx / 27, tap = idx - icp * 27;
        float val = 0.f;
        if (icp < CIN) val = w[((size_t)oc * CIN + icp) * 27 + tap];
        wTo[((size_t)tap * 128 + oc) * CPAD + icp] = f2bf(val);
    }
}

// ---------------------------------------------------------------------------
// Implicit-GEMM 3x3x3 conv via bf16 MFMA (zero padding). Round-8 version:
// LDS double-buffer + counted-vmcnt staging overlap + A/B register double
// buffers, one barrier per chunk, XCD-chunked swizzle, launch_bounds(256,2).
// Block: 128 voxels (2z x 4y x 16x) x 128 oc, 4 waves.
template<int CPAD>
__global__ __launch_bounds__(256, 2) void conv3_mfma_kernel(
    const ushort* __restrict__ xT,   // [VOL][CPAD] bf16
    const ushort* __restrict__ wT,   // [27][128][CPAD] bf16
    const float* __restrict__ bias,  // [128]
    const ushort* __restrict__ zpad, // 16B of zeros
    float* __restrict__ out)         // [128][VOL] fp32
{
    // XCD-chunked swizzle: grid 864, 8 XCDs -> 108 contiguous blocks per XCD.
    const int blk = (blockIdx.x % 8) * 108 + (blockIdx.x / 8);
    const int tx = blk % 3, ty = (blk / 3) % 12, tz = blk / 36;
    const int x0 = tx * 16, y0 = ty * 4, z0 = tz * 2;
    const int t = threadIdx.x;
    const int wave = t >> 6;
    const int lane = t & 63;
    const int l = lane & 15;
    const int q = lane >> 4;
    const int ocw = (wave & 1) * 64;
    const int mzw = wave >> 1;

    __shared__ __align__(16) ushort win[2][432 * 32];   // 54KB double buffer

    // per-lane staging byte offsets into xT (chunk 0), -1 = halo/OOB -> zpad.
    int off[7];
    #pragma unroll
    for (int it = 0; it < 7; it++) {
        const int c = wave + it * 4;
        off[it] = -1;
        if (c < 27) {
            const int i = c * 64 + lane;
            const int p = i >> 2, g = i & 3;
            const int wz = p / 108, pr = p - wz * 108;
            const int wy = pr / 18, wx = pr - wy * 18;
            const int gz = z0 + wz - 1, gy = y0 + wy - 1, gx = x0 + wx - 1;
            if ((unsigned)gx < 48u && (unsigned)gy < 48u && (unsigned)gz < 48u)
                off[it] = ((gz * 2304 + gy * 48 + gx) * CPAD + g * 8) * 2;
        }
    }

    floatx4 acc[4][4];   // acc[oc-subtile j][voxel-subtile mt]
    #pragma unroll
    for (int i = 0; i < 4; i++)
        #pragma unroll
        for (int j = 0; j < 4; j++)
            acc[i][j] = (floatx4){0.f, 0.f, 0.f, 0.f};

    const ushort* wbase = wT + (size_t)(ocw + l) * CPAD + q * 8;
    const int ldsbase = (mzw * 108 + l) * 32 + q * 8;

#define STAGE(CK, BUFP)                                                    \
    {                                                                      \
        const char* xck_ = (const char*)xT + (size_t)(CK) * 64;            \
        _Pragma("unroll")                                                  \
        for (int it_ = 0; it_ < 7; it_++) {                                \
            const int c_ = wave + it_ * 4;                                 \
            if (c_ < 27) {                                                 \
                const ushort* gp_ = (off[it_] >= 0)                        \
                    ? (const ushort*)(xck_ + off[it_]) : zpad;             \
                __builtin_amdgcn_global_load_lds(                          \
                    (const __attribute__((address_space(1))) uint32_t*)gp_,\
                    (__attribute__((address_space(3))) uint32_t*)((BUFP) + c_ * 512 + lane * 8), \
                    16, 0, 0);                                             \
            }                                                              \
        }                                                                  \
    }

    const int NCH = CPAD / 32;

    STAGE(0, &win[0][0]);
    __syncthreads();

    #pragma unroll 1
    for (int ck = 0; ck < NCH; ck++) {
        const ushort* cbuf = &win[ck & 1][0];
        ushort* nbuf = &win[(ck + 1) & 1][0];
        const ushort* wck = wbase + ck * 32;

        short8 A0[4], A1[4];
        A0[0] = *(const short8*)(wck);
        A0[1] = *(const short8*)(wck + 16 * CPAD);
        A0[2] = *(const short8*)(wck + 32 * CPAD);
        A0[3] = *(const short8*)(wck + 48 * CPAD);

        short8 B0[4], B1[4];
        B0[0] = *(const short8*)(&cbuf[ldsbase +    0]);
        B0[1] = *(const short8*)(&cbuf[ldsbase +  576]);
        B0[2] = *(const short8*)(&cbuf[ldsbase + 1152]);
        B0[3] = *(const short8*)(&cbuf[ldsbase + 1728]);

        if (ck + 1 < NCH) STAGE(ck + 1, nbuf);

#define CONV_BODY(TP, AU, AL, BU, BL)                                      \
        {                                                                  \
            const int tpn_ = (TP) + 1;                                     \
            if (tpn_ < 27) {                                               \
                const ushort* wp_ = wck + (size_t)tpn_ * (128 * CPAD);     \
                AL[0] = *(const short8*)(wp_);                             \
                AL[1] = *(const short8*)(wp_ + 16 * CPAD);                 \
                AL[2] = *(const short8*)(wp_ + 32 * CPAD);                 \
                AL[3] = *(const short8*)(wp_ + 48 * CPAD);                 \
                const int dzn_ = tpn_ / 9;                                 \
                const int dyn_ = (tpn_ / 3) % 3;                           \
                const int dxn_ = tpn_ % 3;                                 \
                const int pbn_ = ldsbase + (dzn_ * 108 + dyn_ * 18 + dxn_) * 32; \
                BL[0] = *(const short8*)(&cbuf[pbn_ +    0]);              \
                BL[1] = *(const short8*)(&cbuf[pbn_ +  576]);              \
                BL[2] = *(const short8*)(&cbuf[pbn_ + 1152]);              \
                BL[3] = *(const short8*)(&cbuf[pbn_ + 1728]);              \
            }                                                              \
            acc[0][0] = __builtin_amdgcn_mfma_f32_16x16x32_bf16(AU[0], BU[0], acc[0][0], 0, 0, 0); \
            acc[1][0] = __builtin_amdgcn_mfma_f32_16x16x32_bf16(AU[1], BU[0], acc[1][0], 0, 0, 0); \
            acc[2][0] = __builtin_amdgcn_mfma_f32_16x16x32_bf16(AU[2], BU[0], acc[2][0], 0, 0, 0); \
            acc[3][0] = __builtin_amdgcn_mfma_f32_16x16x32_bf16(AU[3], BU[0], acc[3][0], 0, 0, 0); \
            acc[0][1] = __builtin_amdgcn_mfma_f32_16x16x32_bf16(AU[0], BU[1], acc[0][1], 0, 0, 0); \
            acc[1][1] = __builtin_amdgcn_mfma_f32_16x16x32_bf16(AU[1], BU[1], acc[1][1], 0, 0, 0); \
            acc[2][1] = __builtin_amdgcn_mfma_f32_16x16x32_bf16(AU[2], BU[1], acc[2][1], 0, 0, 0); \
            acc[3][1] = __builtin_amdgcn_mfma_f32_16x16x32_bf16(AU[3], BU[1], acc[3][1], 0, 0, 0); \
            acc[0][2] = __builtin_amdgcn_mfma_f32_16x16x32_bf16(AU[0], BU[2], acc[0][2], 0, 0, 0); \
            acc[1][2] = __builtin_amdgcn_mfma_f32_16x16x32_bf16(AU[1], BU[2], acc[1][2], 0, 0, 0); \
            acc[2][2] = __builtin_amdgcn_mfma_f32_16x16x32_bf16(AU[2], BU[2], acc[2][2], 0, 0, 0); \
            acc[3][2] = __builtin_amdgcn_mfma_f32_16x16x32_bf16(AU[3], BU[2], acc[3][2], 0, 0, 0); \
            acc[0][3] = __builtin_amdgcn_mfma_f32_16x16x32_bf16(AU[0], BU[3], acc[0][3], 0, 0, 0); \
            acc[1][3] = __builtin_amdgcn_mfma_f32_16x16x32_bf16(AU[1], BU[3], acc[1][3], 0, 0, 0); \
            acc[2][3] = __builtin_amdgcn_mfma_f32_16x16x32_bf16(AU[2], BU[3], acc[2][3], 0, 0, 0); \
            acc[3][3] = __builtin_amdgcn_mfma_f32_16x16x32_bf16(AU[3], BU[3], acc[3][3], 0, 0, 0); \
        }

        #pragma unroll 1
        for (int tg = 0; tg < 13; tg++) {
            const int tp = tg * 2;
            CONV_BODY(tp, A0, A1, B0, B1);
            CONV_BODY(tp + 1, A1, A0, B1, B0);
        }
        CONV_BODY(26, A0, A1, B0, B1);
#undef CONV_BODY

        __syncthreads();
    }
#undef STAGE

    #pragma unroll
    for (int nt = 0; nt < 4; nt++) {
        const int ocb = ocw + nt * 16 + q * 4;
        const float4 bv = *(const float4*)(bias + ocb);
        #pragma unroll
        for (int mt = 0; mt < 4; mt++) {
            const int v = (z0 + mzw) * 2304 + (y0 + mt) * 48 + x0 + l;
            out[(size_t)(ocb + 0) * VOL + v] = acc[nt][mt][0] + bv.x;
            out[(size_t)(ocb + 1) * VOL + v] = acc[nt][mt][1] + bv.y;
            out[(size_t)(ocb + 2) * VOL + v] = acc[nt][mt][2] + bv.z;
            out[(size_t)(ocb + 3) * VOL + v] = acc[nt][mt][3] + bv.w;
        }
    }
}

// ---------------------------------------------------------------------------
// Two-phase per-channel stats. Phase 1: grid (128, 8) partial sums.
__global__ __launch_bounds__(256) void chan_stats_part_kernel(
    const float* __restrict__ x, float* __restrict__ pstats /* [128][8][2] */)
{
    const int c = blockIdx.x, g = blockIdx.y;
    const float4* p = (const float4*)(x + (size_t)c * VOL) + g * 3456;
    float s = 0.f, s2 = 0.f;
    #pragma unroll
    for (int j = 0; j < 14; j++) {
        const int i = threadIdx.x + j * 256;
        if (i < 3456) {
            const float4 v = p[i];
            s += v.x + v.y + v.z + v.w;
            s2 = fmaf(v.x, v.x, fmaf(v.y, v.y, fmaf(v.z, v.z, fmaf(v.w, v.w, s2))));
        }
    }
    s  += __shfl_down(s, 32);  s  += __shfl_down(s, 16);
    s  += __shfl_down(s, 8);   s  += __shfl_down(s, 4);
    s  += __shfl_down(s, 2);   s  += __shfl_down(s, 1);
    s2 += __shfl_down(s2, 32); s2 += __shfl_down(s2, 16);
    s2 += __shfl_down(s2, 8);  s2 += __shfl_down(s2, 4);
    s2 += __shfl_down(s2, 2);  s2 += __shfl_down(s2, 1);
    __shared__ float rs[4], rs2[4];
    if ((threadIdx.x & 63) == 0) {
        rs[threadIdx.x >> 6] = s;
        rs2[threadIdx.x >> 6] = s2;
    }
    __syncthreads();
    if (threadIdx.x == 0) {
        pstats[(c * 8 + g) * 2]     = rs[0] + rs[1] + rs[2] + rs[3];
        pstats[(c * 8 + g) * 2 + 1] = rs2[0] + rs2[1] + rs2[2] + rs2[3];
    }
}

// Phase 2: 1 block, 128 threads -> mean/rstd.
__global__ __launch_bounds__(128) void chan_stats_fin_kernel(
    const float* __restrict__ pstats, float* __restrict__ stats /* [128][2] */)
{
    const int c = threadIdx.x;
    float s = 0.f, s2 = 0.f;
    #pragma unroll
    for (int g = 0; g < 8; g++) {
        s  += pstats[(c * 8 + g) * 2];
        s2 += pstats[(c * 8 + g) * 2 + 1];
    }
    const float mean = s / (float)VOL;
    const float var  = s2 / (float)VOL - mean * mean;
    stats[c * 2]     = mean;
    stats[c * 2 + 1] = rsqrtf(var + 1e-5f);
}

__device__ __forceinline__ float gelu_exact(float h)
{
    return 0.5f * h * (1.f + erff(h * 0.70710678118654752f));
}

// Elementwise instance-norm apply + exact GELU (final output, fp32).
__global__ __launch_bounds__(256) void norm_gelu_kernel(
    const float* __restrict__ x, const float* __restrict__ stats,
    float* __restrict__ out)
{
    const size_t i = (size_t)blockIdx.x * 256 + threadIdx.x;  // float4 index
    const int c = (int)(i / (VOL / 4));
    const float mean = stats[c * 2], rstd = stats[c * 2 + 1];
    const float4 xv = ((const float4*)x)[i];
    float4 o;
    o.x = gelu_exact((xv.x - mean) * rstd);
    o.y = gelu_exact((xv.y - mean) * rstd);
    o.z = gelu_exact((xv.z - mean) * rstd);
    o.w = gelu_exact((xv.w - mean) * rstd);
    ((float4*)out)[i] = o;
}

// ---------------------------------------------------------------------------
// Fused: instance-norm apply + GELU + transpose [128][VOL] fp32 -> [VOL][128]
// bf16 (32x32 LDS tiles).
__global__ __launch_bounds__(256) void norm_gelu_transpose_kernel(
    const float* __restrict__ x, const float* __restrict__ stats,
    ushort* __restrict__ outT)
{
    __shared__ float tile[32][33];
    const int v0 = blockIdx.x * 32;
    const int c0 = blockIdx.y * 32;
    const int t = threadIdx.x;
    const int vl = t & 31, cl = t >> 5;
    #pragma unroll
    for (int i = 0; i < 4; i++) {
        const int c = c0 + cl + i * 8;
        const float mean = stats[c * 2], rstd = stats[c * 2 + 1];
        const float val = x[(size_t)c * VOL + v0 + vl];
        tile[cl + i * 8][vl] = gelu_exact((val - mean) * rstd);
    }
    __syncthreads();
    const int vw = t >> 3, cg = t & 7;
    ushort4 o;
    o.x = f2bf(tile[cg * 4 + 0][vw]);
    o.y = f2bf(tile[cg * 4 + 1][vw]);
    o.z = f2bf(tile[cg * 4 + 2][vw]);
    o.w = f2bf(tile[cg * 4 + 3][vw]);
    *(ushort4*)(outT + (size_t)(v0 + vw) * 128 + c0 + cg * 4) = o;
}

// ---------------------------------------------------------------------------
extern "C" void kernel_launch(void* const* d_in, const int* in_sizes, int n_in,
                              void* d_out, int out_size, void* d_ws, size_t ws_size,
                              hipStream_t stream)
{
    const float* src = (const float*)d_in[0];
    const float* tgt = (const float*)d_in[1];
    const float* psw = (const float*)d_in[2];
    const float* psb = (const float*)d_in[3];
    const float* ptw = (const float*)d_in[4];
    const float* ptb = (const float*)d_in[5];
    const float* e1w = (const float*)d_in[6];
    const float* e1b = (const float*)d_in[7];
    const float* e2w = (const float*)d_in[8];
    const float* e2b = (const float*)d_in[9];

    float* ws = (float*)d_ws;
    // Workspace (float-unit offsets; V = VOL):
    //   sp/tp fp16 [0,64V)        dead after corr -> h1 (fp32) reuses [0,128V)
    //   featT bf16 [128V,304V)    dead after conv1 -> h2 reuses [128V,256V)
    //   h1T bf16 [304V,368V)
    //   w1T bf16 [368V..), w2T, stats, pstats, zpad
    _Float16* sp  = (_Float16*)ws;
    _Float16* tp  = (_Float16*)(ws + (size_t)32 * VOL);
    ushort* featT = (ushort*)(ws + (size_t)128 * VOL);
    float*  h1    = ws;
    float*  h2    = ws + (size_t)128 * VOL;
    ushort* h1T   = (ushort*)(ws + (size_t)304 * VOL);
    float*  w1Tf  = ws + (size_t)368 * VOL;
    ushort* w1T   = (ushort*)w1Tf;
    float*  w2Tf  = w1Tf + 608256;           // 27*128*352 ushorts
    ushort* w2T   = (ushort*)w2Tf;
    float*  stats = w2Tf + 221184;           // 27*128*128 ushorts
    float*  pstats = stats + 256;            // 128*8*2 floats
    float*  zpadf  = pstats + 2048;          // 16B zero pad for conv staging
    const ushort* zpad = (const ushort*)zpadf;

    wprep_kernel<346, 352><<<128, 256, 0, stream>>>(e1w, w1T, zpadf);
    wprep_kernel<128, 128><<<128, 256, 0, stream>>>(e2w, w2T, zpadf);

    proj_l2norm_kernel<<<432, 256, 0, stream>>>(src, psw, psb, sp);
    proj_l2norm_kernel<<<432, 256, 0, stream>>>(tgt, ptw, ptb, tp);
    corr_mfma_kernel<<<VOL / 16, 64, 0, stream>>>(sp, tp, featT);

    conv3_mfma_kernel<352><<<864, 256, 0, stream>>>(featT, w1T, e1b, zpad, h1);
    chan_stats_part_kernel<<<dim3(128, 8), 256, 0, stream>>>(h1, pstats);
    chan_stats_fin_kernel<<<1, 128, 0, stream>>>(pstats, stats);
    norm_gelu_transpose_kernel<<<dim3(3456, 4), 256, 0, stream>>>(h1, stats, h1T);

    conv3_mfma_kernel<128><<<864, 256, 0, stream>>>(h1T, w2T, e2b, zpad, h2);
    chan_stats_part_kernel<<<dim3(128, 8), 256, 0, stream>>>(h2, pstats);
    chan_stats_fin_kernel<<<1, 128, 0, stream>>>(pstats, stats);
    norm_gelu_kernel<<<(128 * VOL) / 1024, 256, 0, stream>>>(h2, stats, (float*)d_out);
}